// Round 1
// baseline (4370.377 us; speedup 1.0000x reference)
//
#include <hip/hip_runtime.h>
#include <hip/hip_bf16.h>

#define B_SZ 1024
#define T_SZ 256
#define C_SZ 384
#define H_SZ 64

// ---------------------------------------------------------------------------
// Kernel 1: QKV projection. One block per (b,t) row. 192 threads = 3 mats x 64.
// x row staged in LDS; each thread does a 384-MAC fp32 dot; result stored bf16.
// ---------------------------------------------------------------------------
__global__ void proj_kernel(const float* __restrict__ x,
                            const float* __restrict__ Wk,
                            const float* __restrict__ Wq,
                            const float* __restrict__ Wv,
                            __hip_bfloat16* __restrict__ q,
                            __hip_bfloat16* __restrict__ k,
                            __hip_bfloat16* __restrict__ v) {
    __shared__ float xrow[C_SZ];
    const int row = blockIdx.x;                    // 0 .. B*T-1
    const float* xp = x + (size_t)row * C_SZ;
    for (int i = threadIdx.x; i < C_SZ; i += blockDim.x) xrow[i] = xp[i];
    __syncthreads();

    const int tid = threadIdx.x;                   // 0..191
    const int h   = tid & 63;
    const int m   = tid >> 6;                      // 0:k 1:q 2:v
    const float* W = (m == 0) ? Wk : (m == 1) ? Wq : Wv;

    float acc = 0.f;
#pragma unroll 8
    for (int c = 0; c < C_SZ; ++c) {
        acc += xrow[c] * W[c * H_SZ + h];          // W col read coalesced across h
    }

    __hip_bfloat16* o = (m == 0) ? k : (m == 1) ? q : v;
    o[(size_t)row * H_SZ + h] = __float2bfloat16(acc);
}

// ---------------------------------------------------------------------------
// Kernel 2: causal attention for one (b, t) query row per block. 256 threads.
//   - thread j computes s_j = q_row . k_j   (j <= t, else -inf)
//   - block tree-reduce max, exp, tree-reduce sum
//   - PV: 64 h-lanes x 4 j-chunks partial sums, reduce, divide, store f32
// ---------------------------------------------------------------------------
__global__ void attn_kernel(const __hip_bfloat16* __restrict__ q,
                            const __hip_bfloat16* __restrict__ k,
                            const __hip_bfloat16* __restrict__ v,
                            float* __restrict__ out) {
    const int b = blockIdx.x >> 8;                 // / 256
    const int t = blockIdx.x & 255;
    const int tid = threadIdx.x;

    __shared__ float qrow[H_SZ];
    __shared__ float p[T_SZ];
    __shared__ float red[T_SZ];

    const __hip_bfloat16* qp = q + ((size_t)b * T_SZ + t) * H_SZ;
    if (tid < H_SZ) qrow[tid] = __bfloat162float(qp[tid]);
    __syncthreads();

    // ---- scores ----
    const int j = tid;
    float s = -INFINITY;
    if (j <= t) {
        const __hip_bfloat16* kp = k + ((size_t)b * T_SZ + j) * H_SZ;
        float acc = 0.f;
#pragma unroll 8
        for (int c = 0; c < H_SZ; ++c) acc += qrow[c] * __bfloat162float(kp[c]);
        s = acc * 0.05103103630798288f;            // 1/sqrt(384)  (scale uses C)
    }

    // ---- max reduce ----
    red[tid] = s;
    __syncthreads();
    for (int off = 128; off > 0; off >>= 1) {
        if (tid < off) red[tid] = fmaxf(red[tid], red[tid + off]);
        __syncthreads();
    }
    const float mx = red[0];
    __syncthreads();

    // ---- exp + sum reduce ----
    const float e = (j <= t) ? __expf(s - mx) : 0.f;
    p[tid]  = e;
    red[tid] = e;
    __syncthreads();
    for (int off = 128; off > 0; off >>= 1) {
        if (tid < off) red[tid] += red[tid + off];
        __syncthreads();
    }
    const float denom = red[0];
    __syncthreads();

    // ---- PV: h = tid&63, chunk = tid>>6 covers 64 j each ----
    const int h     = tid & 63;
    const int chunk = tid >> 6;
    float acc = 0.f;
    const __hip_bfloat16* vb = v + (size_t)b * T_SZ * H_SZ;
#pragma unroll 4
    for (int jj = chunk * 64; jj < chunk * 64 + 64; ++jj) {
        acc += p[jj] * __bfloat162float(vb[jj * H_SZ + h]);   // coalesced over h
    }
    red[tid] = acc;
    __syncthreads();
    if (tid < H_SZ) {
        float o = red[tid] + red[tid + 64] + red[tid + 128] + red[tid + 192];
        out[((size_t)b * T_SZ + t) * H_SZ + tid] = o / denom;
    }
}

extern "C" void kernel_launch(void* const* d_in, const int* in_sizes, int n_in,
                              void* d_out, int out_size, void* d_ws, size_t ws_size,
                              hipStream_t stream) {
    const float* x  = (const float*)d_in[0];
    const float* Wk = (const float*)d_in[1];
    const float* Wq = (const float*)d_in[2];
    const float* Wv = (const float*)d_in[3];
    float* out = (float*)d_out;

    const size_t per = (size_t)B_SZ * T_SZ * H_SZ;   // 16.7M elems
    __hip_bfloat16* q = (__hip_bfloat16*)d_ws;
    __hip_bfloat16* k = q + per;
    __hip_bfloat16* v = k + per;

    proj_kernel<<<B_SZ * T_SZ, 192, 0, stream>>>(x, Wk, Wq, Wv, q, k, v);
    attn_kernel<<<B_SZ * T_SZ, 256, 0, stream>>>(q, k, v, out);
}

// Round 3
// 634.111 us; speedup vs baseline: 6.8921x; 6.8921x over previous
//
#include <hip/hip_runtime.h>

#define Bb 1024
#define Tt 256
#define Cc 384
#define Hh 64
#define SCALE 0.05103103630798288f   // 384^-0.5 (reference scales by embed dim C)

typedef __attribute__((ext_vector_type(8))) short bf16x8;
typedef __attribute__((ext_vector_type(4))) float f32x4;
typedef __attribute__((ext_vector_type(4))) unsigned short u16x4;
typedef unsigned short ushort_t;

__device__ __forceinline__ unsigned short f2bf(float f) {
    unsigned int u = __float_as_uint(f);
    u += 0x7fffu + ((u >> 16) & 1u);          // RNE
    return (unsigned short)(u >> 16);
}

// byte address in a 128B-row LDS tile, XOR-swizzled (T2 / G4 pattern)
__device__ __forceinline__ int swz(int row, int colbytes) {
    return (row * 128 + colbytes) ^ ((row & 7) << 4);
}

__device__ __forceinline__ void gll16(const void* g, void* l) {
    __builtin_amdgcn_global_load_lds((__attribute__((address_space(1))) void*)g,
                                     (__attribute__((address_space(3))) void*)l,
                                     16, 0, 0);
}

// ---------------------------------------------------------------------------
// Prep: W[384][64] f32 x3  ->  Wt[192][384] bf16 (n-major, k-contiguous).
// n<64: Wk, n<128: Wq, else Wv.  Wt lives in d_out (overwritten later by attn).
// ---------------------------------------------------------------------------
__global__ __launch_bounds__(384) void prep_kernel(const float* __restrict__ Wk,
                                                   const float* __restrict__ Wq,
                                                   const float* __restrict__ Wv,
                                                   ushort_t* __restrict__ Wt) {
    const int n = blockIdx.x;    // 0..191
    const int c = threadIdx.x;   // 0..383
    const float* W = (n < 64) ? Wk : (n < 128) ? Wq : Wv;
    Wt[n * Cc + c] = f2bf(W[c * Hh + (n & 63)]);
}

// ---------------------------------------------------------------------------
// Projection GEMM: out[262144,192] = x[262144,384] @ W. BM=64, BN=192, BK=64.
// 4 waves; wave w owns 16 rows x 192 cols = 12 C-fragments.
// k,q stored [B*T][64] bf16; v stored TRANSPOSED Vt[b][64h][256t] bf16.
// ---------------------------------------------------------------------------
__global__ __launch_bounds__(256) void proj_kernel(const float* __restrict__ x,
                                                   const ushort_t* __restrict__ Wt,
                                                   ushort_t* __restrict__ kbuf,
                                                   ushort_t* __restrict__ qbuf,
                                                   ushort_t* __restrict__ vtbuf) {
    __shared__ ushort_t xs[64 * 64];     // 8 KB, swizzled
    __shared__ ushort_t ws[192 * 64];    // 24 KB, swizzled
    const int tid  = threadIdx.x;
    const int lane = tid & 63;
    const int w    = tid >> 6;
    const long m0  = (long)blockIdx.x * 64;

    f32x4 acc[12];
#pragma unroll
    for (int i = 0; i < 12; ++i) acc[i] = (f32x4){0.f, 0.f, 0.f, 0.f};

    const int xrow = tid >> 2;            // 0..63
    const int xcg  = (tid & 3) * 16;      // col group (floats)

    for (int ks = 0; ks < 6; ++ks) {
        const int c0 = ks * 64;
        __syncthreads();
        // x tile: f32 -> bf16, reg-staged, swizzled write
        const float* xp = x + (m0 + xrow) * Cc + c0 + xcg;
#pragma unroll
        for (int u = 0; u < 4; ++u) {
            float4 f = *(const float4*)(xp + u * 4);
            u16x4 h = { f2bf(f.x), f2bf(f.y), f2bf(f.z), f2bf(f.w) };
            *(u16x4*)((char*)xs + swz(xrow, (xcg + u * 4) * 2)) = h;
        }
        // W tile: global_load_lds, linear dest + inverse-swizzled source
#pragma unroll
        for (int it = 0; it < 6; ++it) {
            const int i = it * 256 + tid;
            const int n = i >> 3, s = i & 7;
            const ushort_t* g = Wt + n * Cc + c0 + ((s ^ (n & 7)) * 8);
            gll16(g, (char*)ws + (it * 256 + w * 64) * 16);
        }
        __syncthreads();
        const int arow = w * 16 + (lane & 15);
#pragma unroll
        for (int kk = 0; kk < 2; ++kk) {
            const int kb2 = (kk * 32 + (lane >> 4) * 8) * 2;
            bf16x8 a = *(const bf16x8*)((char*)xs + swz(arow, kb2));
#pragma unroll
            for (int nf = 0; nf < 12; ++nf) {
                const int brow = nf * 16 + (lane & 15);
                bf16x8 b = *(const bf16x8*)((char*)ws + swz(brow, kb2));
                acc[nf] = __builtin_amdgcn_mfma_f32_16x16x32_bf16(a, b, acc[nf], 0, 0, 0);
            }
        }
    }

    // epilogue: C layout col=lane&15, row=(lane>>4)*4+r  [m89]
    const long b    = m0 >> 8;
    const int  t0   = (int)(m0 & 255);
    const int  rbase = w * 16 + ((lane >> 4) << 2);
#pragma unroll
    for (int nf = 0; nf < 8; ++nf) {
        ushort_t* obuf = (nf < 4) ? kbuf : qbuf;
        const int n = (nf & 3) * 16 + (lane & 15);
#pragma unroll
        for (int r = 0; r < 4; ++r)
            obuf[(m0 + rbase + r) * Hh + n] = f2bf(acc[nf][r]);
    }
#pragma unroll
    for (int nf = 0; nf < 4; ++nf) {
        const int h = nf * 16 + (lane & 15);
        u16x4 hv = { f2bf(acc[8 + nf][0]), f2bf(acc[8 + nf][1]),
                     f2bf(acc[8 + nf][2]), f2bf(acc[8 + nf][3]) };
        *(u16x4*)(vtbuf + (b * 64 + h) * Tt + t0 + rbase) = hv;   // contiguous in t
    }
}

// ---------------------------------------------------------------------------
// Attention: block = (batch b, 64-row q-tile qt). 4 waves; wave w owns 16 q-rows.
// Full-row S in registers (no online softmax). PV via O^T = V^T * P^T.
// ---------------------------------------------------------------------------
__global__ __launch_bounds__(256) void attn_kernel(const ushort_t* __restrict__ qbuf,
                                                   const ushort_t* __restrict__ kbuf,
                                                   const ushort_t* __restrict__ vtbuf,
                                                   float* __restrict__ out) {
    __shared__ ushort_t kv[64 * 64];         // 8 KB: K tile then Vt tile
    __shared__ ushort_t pbuf[4][16 * 256];   // 32 KB: per-wave P, swizzled 512B rows
    __shared__ float dn[4][16];
    const int tid  = threadIdx.x;
    const int lane = tid & 63;
    const int w    = tid >> 6;
    const long b   = blockIdx.x >> 2;
    const int qt   = blockIdx.x & 3;
    const int qw   = qt * 64 + w * 16;

    // Q fragments straight from global (row-major, k-contiguous)
    bf16x8 aq[2];
    const int qrow = qw + (lane & 15);
#pragma unroll
    for (int kk = 0; kk < 2; ++kk)
        aq[kk] = *(const bf16x8*)(qbuf + (b * Tt + qrow) * Hh + kk * 32 + (lane >> 4) * 8);

    f32x4 sfr[4][4];
#pragma unroll
    for (int jt = 0; jt < 4; ++jt)
#pragma unroll
        for (int nf = 0; nf < 4; ++nf) sfr[jt][nf] = (f32x4){0.f, 0.f, 0.f, 0.f};

    // ---- S = Q K^T over kv tiles (uniform predication keeps indices static) ----
#pragma unroll
    for (int jt = 0; jt < 4; ++jt) {
        if (jt <= qt) {
            __syncthreads();
#pragma unroll
            for (int it = 0; it < 2; ++it) {
                const int i = it * 256 + tid;
                const int r = i >> 3, s = i & 7;
                const ushort_t* g = kbuf + (b * Tt + jt * 64 + r) * Hh + ((s ^ (r & 7)) * 8);
                gll16(g, (char*)kv + (it * 256 + w * 64) * 16);
            }
            __syncthreads();
#pragma unroll
            for (int kk = 0; kk < 2; ++kk) {
                const int kb2 = (kk * 32 + (lane >> 4) * 8) * 2;
#pragma unroll
                for (int nf = 0; nf < 4; ++nf) {
                    const int brow = nf * 16 + (lane & 15);
                    bf16x8 bb = *(const bf16x8*)((char*)kv + swz(brow, kb2));
                    sfr[jt][nf] = __builtin_amdgcn_mfma_f32_16x16x32_bf16(aq[kk], bb, sfr[jt][nf], 0, 0, 0);
                }
            }
        }
    }

    // ---- mask + scale + softmax + P->bf16 LDS (per-wave) ----
#pragma unroll
    for (int r = 0; r < 4; ++r) {
        const int prow = ((lane >> 4) << 2) + r;   // S-row within wave tile
        const int qr   = qw + prow;                // global q row
        float mx = -1e30f;
#pragma unroll
        for (int jt = 0; jt < 4; ++jt) {
            if (jt <= qt) {
#pragma unroll
                for (int nf = 0; nf < 4; ++nf) {
                    const int j = jt * 64 + nf * 16 + (lane & 15);
                    float s = sfr[jt][nf][r] * SCALE;
                    if (j > qr) s = -1e30f;        // causal mask
                    sfr[jt][nf][r] = s;
                    mx = fmaxf(mx, s);
                }
            }
        }
        mx = fmaxf(mx, __shfl_xor(mx, 1));
        mx = fmaxf(mx, __shfl_xor(mx, 2));
        mx = fmaxf(mx, __shfl_xor(mx, 4));
        mx = fmaxf(mx, __shfl_xor(mx, 8));
        float ss = 0.f;
#pragma unroll
        for (int jt = 0; jt < 4; ++jt) {
            if (jt <= qt) {
#pragma unroll
                for (int nf = 0; nf < 4; ++nf) {
                    const float e = __expf(sfr[jt][nf][r] - mx);
                    ss += e;
                    const int pc2 = (jt * 64 + nf * 16 + (lane & 15)) * 2;
                    *(ushort_t*)((char*)pbuf[w] + ((prow * 512 + pc2) ^ ((prow & 7) << 4))) = f2bf(e);
                }
            }
        }
        ss += __shfl_xor(ss, 1);
        ss += __shfl_xor(ss, 2);
        ss += __shfl_xor(ss, 4);
        ss += __shfl_xor(ss, 8);
        if ((lane & 15) == 0) dn[w][prow] = ss;
    }

    // ---- PV: O^T[h][q] = sum_j Vt[h][j] * P[q][j] ----
    f32x4 ot[4];
#pragma unroll
    for (int i = 0; i < 4; ++i) ot[i] = (f32x4){0.f, 0.f, 0.f, 0.f};
#pragma unroll
    for (int jt = 0; jt < 4; ++jt) {
        if (jt <= qt) {
            __syncthreads();
#pragma unroll
            for (int it = 0; it < 2; ++it) {
                const int i = it * 256 + tid;
                const int r = i >> 3, s = i & 7;
                const ushort_t* g = vtbuf + (b * 64 + r) * Tt + jt * 64 + ((s ^ (r & 7)) * 8);
                gll16(g, (char*)kv + (it * 256 + w * 64) * 16);
            }
            __syncthreads();
#pragma unroll
            for (int kk = 0; kk < 2; ++kk) {
                const int pq   = lane & 15;
                const int pc2  = (jt * 64 + kk * 32 + (lane >> 4) * 8) * 2;
                bf16x8 bp = *(const bf16x8*)((char*)pbuf[w] + ((pq * 512 + pc2) ^ ((pq & 7) << 4)));
                const int kb2 = (kk * 32 + (lane >> 4) * 8) * 2;
#pragma unroll
                for (int hb = 0; hb < 4; ++hb) {
                    const int arow = hb * 16 + (lane & 15);
                    bf16x8 av = *(const bf16x8*)((char*)kv + swz(arow, kb2));
                    ot[hb] = __builtin_amdgcn_mfma_f32_16x16x32_bf16(av, bp, ot[hb], 0, 0, 0);
                }
            }
        }
    }

    const float invd = 1.0f / dn[w][lane & 15];
    const int qout = qw + (lane & 15);
#pragma unroll
    for (int hb = 0; hb < 4; ++hb) {
        float4 o;
        o.x = ot[hb][0] * invd; o.y = ot[hb][1] * invd;
        o.z = ot[hb][2] * invd; o.w = ot[hb][3] * invd;
        *(float4*)(out + (b * Tt + qout) * Hh + hb * 16 + ((lane >> 4) << 2)) = o;
    }
}

extern "C" void kernel_launch(void* const* d_in, const int* in_sizes, int n_in,
                              void* d_out, int out_size, void* d_ws, size_t ws_size,
                              hipStream_t stream) {
    const float* x  = (const float*)d_in[0];
    const float* Wk = (const float*)d_in[1];
    const float* Wq = (const float*)d_in[2];
    const float* Wv = (const float*)d_in[3];
    float* out = (float*)d_out;

    const size_t per = (size_t)Bb * Tt * Hh;
    ushort_t* kbuf  = (ushort_t*)d_ws;
    ushort_t* qbuf  = kbuf + per;
    ushort_t* vtbuf = qbuf + per;
    // Wt (192*384 bf16 = 147 KB) lives at the head of d_out: read only by
    // proj_kernel, then fully overwritten by attn_kernel. Avoids assuming
    // ws_size > 3*per*2 (only that much is proven available).
    ushort_t* Wt    = (ushort_t*)d_out;

    prep_kernel<<<192, 384, 0, stream>>>(Wk, Wq, Wv, Wt);
    proj_kernel<<<(Bb * Tt) / 64, 256, 0, stream>>>(x, Wt, kbuf, qbuf, vtbuf);
    attn_kernel<<<Bb * 4, 256, 0, stream>>>(qbuf, kbuf, vtbuf, out);
}